// Round 1
// baseline (3581.553 us; speedup 1.0000x reference)
//
#include <hip/hip_runtime.h>

#define N_NODES 50000
#define DIM     128      // HID; also concat(emb,x_struct) width
#define N_EDGES 800000
#define N_LABEL 200000

// h0[i] = concat(emb[n_id[i]], x_struct[i]) ; one thread per float4 (32 per row)
__global__ void build_h0(const int* __restrict__ n_id,
                         const float* __restrict__ emb,
                         const float* __restrict__ xs,
                         float* __restrict__ h0) {
    int t = blockIdx.x * blockDim.x + threadIdx.x;
    if (t >= N_NODES * 32) return;
    int i = t >> 5, c = t & 31;          // c: float4 index within 128-wide row
    float4 v;
    if (c < 16) {
        int nid = n_id[i];
        v = ((const float4*)emb)[nid * 16 + c];
    } else {
        v = ((const float4*)xs)[i * 16 + (c - 16)];
    }
    ((float4*)h0)[i * 32 + c] = v;
}

__global__ void deg_count(const int* __restrict__ dst, float* __restrict__ deg) {
    int e = blockIdx.x * blockDim.x + threadIdx.x;
    if (e < N_EDGES) atomicAdd(&deg[dst[e]], 1.0f);
}

__global__ void make_rdeg(const float* __restrict__ deg, float* __restrict__ rdeg) {
    int i = blockIdx.x * blockDim.x + threadIdx.x;
    if (i < N_NODES) rdeg[i] = 1.0f / fmaxf(deg[i], 1.0f);
}

// scatter-add: 32 threads per edge, float4 gather + 4 fp32 atomics each
__global__ void aggregate(const int* __restrict__ src, const int* __restrict__ dst,
                          const float* __restrict__ h, float* __restrict__ agg) {
    int t = blockIdx.x * blockDim.x + threadIdx.x;
    int e = t >> 5, c = t & 31;
    if (e >= N_EDGES) return;
    int s = src[e], d = dst[e];
    float4 v = ((const float4*)h)[s * 32 + c];
    float* p = agg + d * DIM + c * 4;
    atomicAdd(p + 0, v.x);
    atomicAdd(p + 1, v.y);
    atomicAdd(p + 2, v.z);
    atomicAdd(p + 3, v.w);
}

// out[i][j] = maybe_relu( (agg[i]·Wl[:,j]) * rdeg[i] + h[i]·Wr[:,j] + b[j] )
// thread per output element; block = 2 rows x 128 cols
template <int RELU>
__global__ void linear_kernel(const float* __restrict__ agg,
                              const float* __restrict__ rdeg,
                              const float* __restrict__ h,
                              const float* __restrict__ Wl,
                              const float* __restrict__ Wr,
                              const float* __restrict__ b,
                              float* __restrict__ out) {
    int t = blockIdx.x * blockDim.x + threadIdx.x;
    int i = t >> 7, j = t & 127;
    if (i >= N_NODES) return;
    const float4* arow = (const float4*)(agg + i * DIM);
    const float4* hrow = (const float4*)(h + i * DIM);
    float accl = 0.f, accr = 0.f;
#pragma unroll 8
    for (int k4 = 0; k4 < 32; ++k4) {
        float4 a = arow[k4];
        float4 x = hrow[k4];
        int k = k4 * 4;
        accl += a.x * Wl[(k + 0) * DIM + j];
        accl += a.y * Wl[(k + 1) * DIM + j];
        accl += a.z * Wl[(k + 2) * DIM + j];
        accl += a.w * Wl[(k + 3) * DIM + j];
        accr += x.x * Wr[(k + 0) * DIM + j];
        accr += x.y * Wr[(k + 1) * DIM + j];
        accr += x.z * Wr[(k + 2) * DIM + j];
        accr += x.w * Wr[(k + 3) * DIM + j];
    }
    float r = accl * rdeg[i] + accr + b[j];
    if (RELU) r = fmaxf(r, 0.f);
    out[i * DIM + j] = r;
}

// logits[e] = dot(h2[esrc[e]], h2[edst[e]]) ; 32 threads/edge + shfl reduce
__global__ void edge_dot(const int* __restrict__ esrc, const int* __restrict__ edst,
                         const float* __restrict__ h2, float* __restrict__ out) {
    int t = blockIdx.x * blockDim.x + threadIdx.x;
    int e = t >> 5, c = t & 31;
    if (e >= N_LABEL) return;
    float4 a  = ((const float4*)h2)[esrc[e] * 32 + c];
    float4 bb = ((const float4*)h2)[edst[e] * 32 + c];
    float p = a.x * bb.x + a.y * bb.y + a.z * bb.z + a.w * bb.w;
#pragma unroll
    for (int off = 16; off; off >>= 1) p += __shfl_down(p, off, 32);
    if (c == 0) out[e] = p;
}

extern "C" void kernel_launch(void* const* d_in, const int* in_sizes, int n_in,
                              void* d_out, int out_size, void* d_ws, size_t ws_size,
                              hipStream_t stream) {
    const int*   n_id     = (const int*)d_in[0];
    const float* x_struct = (const float*)d_in[1];
    const int*   e_idx    = (const int*)d_in[2];   // [2, 800000]
    const int*   eli      = (const int*)d_in[3];   // [2, 200000]
    const float* emb      = (const float*)d_in[4];
    const float* W1l      = (const float*)d_in[5];
    const float* W1r      = (const float*)d_in[6];
    const float* b1       = (const float*)d_in[7];
    const float* W2l      = (const float*)d_in[8];
    const float* W2r      = (const float*)d_in[9];
    const float* b2       = (const float*)d_in[10];
    float* out = (float*)d_out;

    const int* src = e_idx;
    const int* dst = e_idx + N_EDGES;

    const size_t HN = (size_t)N_NODES * DIM;       // 6.4M floats
    float* h0   = (float*)d_ws;
    float* h1   = h0 + HN;
    float* agg  = h1 + HN;
    float* deg  = agg + HN;
    float* rdeg = deg + N_NODES;
    float* h2   = h0;                              // h0 dead after layer-1 linear

    hipMemsetAsync(deg, 0, N_NODES * sizeof(float), stream);
    hipMemsetAsync(agg, 0, HN * sizeof(float), stream);

    build_h0<<<(N_NODES * 32 + 255) / 256, 256, 0, stream>>>(n_id, emb, x_struct, h0);
    deg_count<<<(N_EDGES + 255) / 256, 256, 0, stream>>>(dst, deg);
    make_rdeg<<<(N_NODES + 255) / 256, 256, 0, stream>>>(deg, rdeg);

    // layer 1
    aggregate<<<(N_EDGES * 32 + 255) / 256, 256, 0, stream>>>(src, dst, h0, agg);
    linear_kernel<1><<<(N_NODES * DIM + 255) / 256, 256, 0, stream>>>(
        agg, rdeg, h0, W1l, W1r, b1, h1);

    // layer 2
    hipMemsetAsync(agg, 0, HN * sizeof(float), stream);
    aggregate<<<(N_EDGES * 32 + 255) / 256, 256, 0, stream>>>(src, dst, h1, agg);
    linear_kernel<0><<<(N_NODES * DIM + 255) / 256, 256, 0, stream>>>(
        agg, rdeg, h1, W2l, W2r, b2, h2);

    edge_dot<<<(N_LABEL * 32 + 255) / 256, 256, 0, stream>>>(eli, eli + N_LABEL, h2, out);
}

// Round 2
// 1067.877 us; speedup vs baseline: 3.3539x; 3.3539x over previous
//
#include <hip/hip_runtime.h>

#define N_NODES 50000
#define DIM     128
#define N_EDGES 800000
#define N_LABEL 200000

// h0[i] = concat(emb[n_id[i]], x_struct[i]) ; one thread per float4 (32 per row)
__global__ void build_h0(const int* __restrict__ n_id,
                         const float* __restrict__ emb,
                         const float* __restrict__ xs,
                         float* __restrict__ h0) {
    int t = blockIdx.x * blockDim.x + threadIdx.x;
    if (t >= N_NODES * 32) return;
    int i = t >> 5, c = t & 31;
    float4 v;
    if (c < 16) {
        int nid = n_id[i];
        v = ((const float4*)emb)[nid * 16 + c];
    } else {
        v = ((const float4*)xs)[i * 16 + (c - 16)];
    }
    ((float4*)h0)[i * 32 + c] = v;
}

__global__ void deg_count(const int* __restrict__ dst, int* __restrict__ deg) {
    int e = blockIdx.x * blockDim.x + threadIdx.x;
    if (e < N_EDGES) atomicAdd(&deg[dst[e]], 1);
}

// single-block exclusive scan of deg[0..N_NODES) -> row[0..N_NODES]
__global__ void scan_deg(const int* __restrict__ deg, int* __restrict__ row) {
    __shared__ int wsum[16];
    __shared__ int carry_s;
    int lane = threadIdx.x & 63;
    int wid  = threadIdx.x >> 6;
    if (threadIdx.x == 0) carry_s = 0;
    __syncthreads();
    for (int base = 0; base < N_NODES; base += 1024) {
        int i = base + threadIdx.x;
        int v = (i < N_NODES) ? deg[i] : 0;
        // wave-level inclusive scan
        int s = v;
#pragma unroll
        for (int off = 1; off < 64; off <<= 1) {
            int t = __shfl_up(s, off, 64);
            if (lane >= off) s += t;
        }
        if (lane == 63) wsum[wid] = s;
        __syncthreads();
        if (wid == 0 && lane < 16) {
            int ws = wsum[lane];
#pragma unroll
            for (int off = 1; off < 16; off <<= 1) {
                int t = __shfl_up(ws, off, 64);
                if (lane >= off) ws += t;
            }
            wsum[lane] = ws;   // inclusive over wave sums
        }
        __syncthreads();
        int wbase = (wid > 0) ? wsum[wid - 1] : 0;
        int excl = wbase + s - v;
        if (i < N_NODES) row[i] = carry_s + excl;
        __syncthreads();
        if (threadIdx.x == 1023) carry_s += wsum[15];
        __syncthreads();
    }
    if (threadIdx.x == 0) row[N_NODES] = carry_s;
}

__global__ void csr_fill(const int* __restrict__ src, const int* __restrict__ dst,
                         const int* __restrict__ row, int* __restrict__ cursor,
                         int* __restrict__ csr_src) {
    int e = blockIdx.x * blockDim.x + threadIdx.x;
    if (e >= N_EDGES) return;
    int d = dst[e];
    int pos = atomicAdd(&cursor[d], 1);
    csr_src[row[d] + pos] = src[e];
}

// gather-mean: one wave per node; lane holds float2 slice of the 128-dim row
__global__ void aggregate_csr(const int* __restrict__ row,
                              const int* __restrict__ csr_src,
                              const float* __restrict__ h,
                              float* __restrict__ agg) {
    int wv   = (blockIdx.x * blockDim.x + threadIdx.x) >> 6;
    int lane = threadIdx.x & 63;
    if (wv >= N_NODES) return;
    int beg = row[wv], end = row[wv + 1];
    float ax = 0.f, ay = 0.f;
    for (int b = beg; b < end; b += 64) {
        int cnt = min(64, end - b);
        int idx = (b + lane < end) ? csr_src[b + lane] : 0;
        for (int j = 0; j < cnt; ++j) {
            int s = __shfl(idx, j, 64);
            float2 v = ((const float2*)h)[s * 64 + lane];
            ax += v.x; ay += v.y;
        }
    }
    float rd = 1.0f / fmaxf((float)(end - beg), 1.0f);
    ((float2*)agg)[wv * 64 + lane] = make_float2(ax * rd, ay * rd);
}

// out[i][j] = maybe_relu( agg[i]·Wl[:,j] + h[i]·Wr[:,j] + b[j] )   (agg is already mean)
template <int RELU>
__global__ void linear_kernel(const float* __restrict__ agg,
                              const float* __restrict__ h,
                              const float* __restrict__ Wl,
                              const float* __restrict__ Wr,
                              const float* __restrict__ b,
                              float* __restrict__ out) {
    int t = blockIdx.x * blockDim.x + threadIdx.x;
    int i = t >> 7, j = t & 127;
    if (i >= N_NODES) return;
    const float4* arow = (const float4*)(agg + i * DIM);
    const float4* hrow = (const float4*)(h + i * DIM);
    float accl = 0.f, accr = 0.f;
#pragma unroll 8
    for (int k4 = 0; k4 < 32; ++k4) {
        float4 a = arow[k4];
        float4 x = hrow[k4];
        int k = k4 * 4;
        accl += a.x * Wl[(k + 0) * DIM + j];
        accl += a.y * Wl[(k + 1) * DIM + j];
        accl += a.z * Wl[(k + 2) * DIM + j];
        accl += a.w * Wl[(k + 3) * DIM + j];
        accr += x.x * Wr[(k + 0) * DIM + j];
        accr += x.y * Wr[(k + 1) * DIM + j];
        accr += x.z * Wr[(k + 2) * DIM + j];
        accr += x.w * Wr[(k + 3) * DIM + j];
    }
    float r = accl + accr + b[j];
    if (RELU) r = fmaxf(r, 0.f);
    out[i * DIM + j] = r;
}

__global__ void edge_dot(const int* __restrict__ esrc, const int* __restrict__ edst,
                         const float* __restrict__ h2, float* __restrict__ out) {
    int t = blockIdx.x * blockDim.x + threadIdx.x;
    int e = t >> 5, c = t & 31;
    if (e >= N_LABEL) return;
    float4 a  = ((const float4*)h2)[esrc[e] * 32 + c];
    float4 bb = ((const float4*)h2)[edst[e] * 32 + c];
    float p = a.x * bb.x + a.y * bb.y + a.z * bb.z + a.w * bb.w;
#pragma unroll
    for (int off = 16; off; off >>= 1) p += __shfl_down(p, off, 32);
    if (c == 0) out[e] = p;
}

extern "C" void kernel_launch(void* const* d_in, const int* in_sizes, int n_in,
                              void* d_out, int out_size, void* d_ws, size_t ws_size,
                              hipStream_t stream) {
    const int*   n_id     = (const int*)d_in[0];
    const float* x_struct = (const float*)d_in[1];
    const int*   e_idx    = (const int*)d_in[2];   // [2, N_EDGES]
    const int*   eli      = (const int*)d_in[3];   // [2, N_LABEL]
    const float* emb      = (const float*)d_in[4];
    const float* W1l      = (const float*)d_in[5];
    const float* W1r      = (const float*)d_in[6];
    const float* b1       = (const float*)d_in[7];
    const float* W2l      = (const float*)d_in[8];
    const float* W2r      = (const float*)d_in[9];
    const float* b2       = (const float*)d_in[10];
    float* out = (float*)d_out;

    const int* src = e_idx;
    const int* dst = e_idx + N_EDGES;

    const size_t HN = (size_t)N_NODES * DIM;       // 6.4M floats
    float* h0     = (float*)d_ws;
    float* h1     = h0 + HN;
    float* agg    = h1 + HN;
    int*   deg    = (int*)(agg + HN);
    int*   cursor = deg + N_NODES;
    int*   row    = cursor + N_NODES;              // N_NODES+1
    int*   csr    = row + N_NODES + 1;             // N_EDGES
    float* h2     = h0;                            // h0 dead after layer-1 linear

    hipMemsetAsync(deg, 0, N_NODES * sizeof(int), stream);
    hipMemsetAsync(cursor, 0, N_NODES * sizeof(int), stream);

    build_h0<<<(N_NODES * 32 + 255) / 256, 256, 0, stream>>>(n_id, emb, x_struct, h0);

    // CSR build (once; reused by both layers)
    deg_count<<<(N_EDGES + 255) / 256, 256, 0, stream>>>(dst, deg);
    scan_deg<<<1, 1024, 0, stream>>>(deg, row);
    csr_fill<<<(N_EDGES + 255) / 256, 256, 0, stream>>>(src, dst, row, cursor, csr);

    // layer 1
    aggregate_csr<<<(N_NODES * 64 + 255) / 256, 256, 0, stream>>>(row, csr, h0, agg);
    linear_kernel<1><<<(N_NODES * DIM + 255) / 256, 256, 0, stream>>>(
        agg, h0, W1l, W1r, b1, h1);

    // layer 2
    aggregate_csr<<<(N_NODES * 64 + 255) / 256, 256, 0, stream>>>(row, csr, h1, agg);
    linear_kernel<0><<<(N_NODES * DIM + 255) / 256, 256, 0, stream>>>(
        agg, h1, W2l, W2r, b2, h2);

    edge_dot<<<(N_LABEL * 32 + 255) / 256, 256, 0, stream>>>(eli, eli + N_LABEL, h2, out);
}

// Round 3
// 492.347 us; speedup vs baseline: 7.2744x; 2.1690x over previous
//
#include <hip/hip_runtime.h>

#define N_NODES 50000
#define DIM     128
#define N_EDGES 800000
#define N_LABEL 200000

// h0[i] = concat(emb[n_id[i]], x_struct[i]) ; one thread per float4 (32 per row)
__global__ void build_h0(const int* __restrict__ n_id,
                         const float* __restrict__ emb,
                         const float* __restrict__ xs,
                         float* __restrict__ h0) {
    int t = blockIdx.x * blockDim.x + threadIdx.x;
    if (t >= N_NODES * 32) return;
    int i = t >> 5, c = t & 31;
    float4 v;
    if (c < 16) {
        int nid = n_id[i];
        v = ((const float4*)emb)[nid * 16 + c];
    } else {
        v = ((const float4*)xs)[i * 16 + (c - 16)];
    }
    ((float4*)h0)[i * 32 + c] = v;
}

__global__ void deg_count(const int* __restrict__ dst, int* __restrict__ deg) {
    int e = blockIdx.x * blockDim.x + threadIdx.x;
    if (e < N_EDGES) atomicAdd(&deg[dst[e]], 1);
}

// single-block exclusive scan of deg[0..N_NODES) -> row[0..N_NODES]
__global__ void scan_deg(const int* __restrict__ deg, int* __restrict__ row) {
    __shared__ int wsum[16];
    __shared__ int carry_s;
    int lane = threadIdx.x & 63;
    int wid  = threadIdx.x >> 6;
    if (threadIdx.x == 0) carry_s = 0;
    __syncthreads();
    for (int base = 0; base < N_NODES; base += 1024) {
        int i = base + threadIdx.x;
        int v = (i < N_NODES) ? deg[i] : 0;
        int s = v;
#pragma unroll
        for (int off = 1; off < 64; off <<= 1) {
            int t = __shfl_up(s, off, 64);
            if (lane >= off) s += t;
        }
        if (lane == 63) wsum[wid] = s;
        __syncthreads();
        if (wid == 0 && lane < 16) {
            int ws = wsum[lane];
#pragma unroll
            for (int off = 1; off < 16; off <<= 1) {
                int t = __shfl_up(ws, off, 64);
                if (lane >= off) ws += t;
            }
            wsum[lane] = ws;
        }
        __syncthreads();
        int wbase = (wid > 0) ? wsum[wid - 1] : 0;
        int excl = wbase + s - v;
        if (i < N_NODES) row[i] = carry_s + excl;
        __syncthreads();
        if (threadIdx.x == 1023) carry_s += wsum[15];
        __syncthreads();
    }
    if (threadIdx.x == 0) row[N_NODES] = carry_s;
}

__global__ void csr_fill(const int* __restrict__ src, const int* __restrict__ dst,
                         const int* __restrict__ row, int* __restrict__ cursor,
                         int* __restrict__ csr_src) {
    int e = blockIdx.x * blockDim.x + threadIdx.x;
    if (e >= N_EDGES) return;
    int d = dst[e];
    int pos = atomicAdd(&cursor[d], 1);
    csr_src[row[d] + pos] = src[e];
}

// gather-mean: one wave per node; lane holds float2 slice of the 128-dim row
__global__ void aggregate_csr(const int* __restrict__ row,
                              const int* __restrict__ csr_src,
                              const float* __restrict__ h,
                              float* __restrict__ agg) {
    int wv   = (blockIdx.x * blockDim.x + threadIdx.x) >> 6;
    int lane = threadIdx.x & 63;
    if (wv >= N_NODES) return;
    int beg = row[wv], end = row[wv + 1];
    float ax = 0.f, ay = 0.f;
    for (int b = beg; b < end; b += 64) {
        int cnt = min(64, end - b);
        int idx = (b + lane < end) ? csr_src[b + lane] : 0;
        for (int j = 0; j < cnt; ++j) {
            int s = __shfl(idx, j, 64);
            float2 v = ((const float2*)h)[s * 64 + lane];
            ax += v.x; ay += v.y;
        }
    }
    float rd = 1.0f / fmaxf((float)(end - beg), 1.0f);
    ((float2*)agg)[wv * 64 + lane] = make_float2(ax * rd, ay * rd);
}

// Tiled GEMM: out[M,128] = relu?( agg@Wl + h@Wr + b )
// BM=64, BN=128, BK=16; 256 threads; thread computes 8 rows x 4 cols.
#define BM 64
#define BK 16
#define BMP 68   // padded leading dim for As (2-way bank alias only — free)

template <int RELU>
__global__ __launch_bounds__(256)
void linear_tiled(const float* __restrict__ agg,
                  const float* __restrict__ h,
                  const float* __restrict__ Wl,
                  const float* __restrict__ Wr,
                  const float* __restrict__ b,
                  float* __restrict__ out) {
    __shared__ float As[BK][BMP];    // A tile, transposed (k major, m minor)
    __shared__ float Ws[BK][128];    // W tile
    const int tid = threadIdx.x;
    const int tx = tid & 31;         // n-group: cols 4*tx .. 4*tx+3
    const int ty = tid >> 5;         // m-group: rows 8*ty .. 8*ty+7
    const int i0 = blockIdx.x * BM;

    float acc[8][4];
#pragma unroll
    for (int m = 0; m < 8; ++m)
#pragma unroll
        for (int n = 0; n < 4; ++n) acc[m][n] = 0.f;

    const float* Aarr[2] = {agg, h};
    const float* Warr[2] = {Wl, Wr};

    for (int phase = 0; phase < 2; ++phase) {
        const float* A = Aarr[phase];
        const float* W = Warr[phase];
        for (int k0 = 0; k0 < DIM; k0 += BK) {
            // stage A: 64 rows x 16 k; one float4 per thread, scattered to transposed LDS
            {
                int r = tid >> 2;        // 0..63  (row within tile)
                int q = tid & 3;         // 0..3   (k quad)
                int row = i0 + r;
                float4 v = make_float4(0.f, 0.f, 0.f, 0.f);
                if (row < N_NODES) v = *(const float4*)(A + (size_t)row * DIM + k0 + q * 4);
                As[q * 4 + 0][r] = v.x;
                As[q * 4 + 1][r] = v.y;
                As[q * 4 + 2][r] = v.z;
                As[q * 4 + 3][r] = v.w;
            }
            // stage W: 16 k x 128 n; two float4 per thread, coalesced
            {
                int rr = tid >> 5;       // 0..7
                int c4 = tid & 31;
                *(float4*)&Ws[rr][c4 * 4]     = *(const float4*)(W + (size_t)(k0 + rr) * DIM + c4 * 4);
                *(float4*)&Ws[rr + 8][c4 * 4] = *(const float4*)(W + (size_t)(k0 + rr + 8) * DIM + c4 * 4);
            }
            __syncthreads();
#pragma unroll
            for (int k = 0; k < BK; ++k) {
                float4 a0 = *(const float4*)&As[k][ty * 8];
                float4 a1 = *(const float4*)&As[k][ty * 8 + 4];
                float4 w  = *(const float4*)&Ws[k][tx * 4];
                float am[8] = {a0.x, a0.y, a0.z, a0.w, a1.x, a1.y, a1.z, a1.w};
                float wn[4] = {w.x, w.y, w.z, w.w};
#pragma unroll
                for (int m = 0; m < 8; ++m)
#pragma unroll
                    for (int n = 0; n < 4; ++n) acc[m][n] += am[m] * wn[n];
            }
            __syncthreads();
        }
    }

    float4 bb = *(const float4*)&b[tx * 4];
#pragma unroll
    for (int m = 0; m < 8; ++m) {
        int row = i0 + ty * 8 + m;
        if (row < N_NODES) {
            float4 r;
            r.x = acc[m][0] + bb.x;
            r.y = acc[m][1] + bb.y;
            r.z = acc[m][2] + bb.z;
            r.w = acc[m][3] + bb.w;
            if (RELU) {
                r.x = fmaxf(r.x, 0.f); r.y = fmaxf(r.y, 0.f);
                r.z = fmaxf(r.z, 0.f); r.w = fmaxf(r.w, 0.f);
            }
            *(float4*)(out + (size_t)row * DIM + tx * 4) = r;
        }
    }
}

__global__ void edge_dot(const int* __restrict__ esrc, const int* __restrict__ edst,
                         const float* __restrict__ h2, float* __restrict__ out) {
    int t = blockIdx.x * blockDim.x + threadIdx.x;
    int e = t >> 5, c = t & 31;
    if (e >= N_LABEL) return;
    float4 a  = ((const float4*)h2)[esrc[e] * 32 + c];
    float4 bb = ((const float4*)h2)[edst[e] * 32 + c];
    float p = a.x * bb.x + a.y * bb.y + a.z * bb.z + a.w * bb.w;
#pragma unroll
    for (int off = 16; off; off >>= 1) p += __shfl_down(p, off, 32);
    if (c == 0) out[e] = p;
}

extern "C" void kernel_launch(void* const* d_in, const int* in_sizes, int n_in,
                              void* d_out, int out_size, void* d_ws, size_t ws_size,
                              hipStream_t stream) {
    const int*   n_id     = (const int*)d_in[0];
    const float* x_struct = (const float*)d_in[1];
    const int*   e_idx    = (const int*)d_in[2];   // [2, N_EDGES]
    const int*   eli      = (const int*)d_in[3];   // [2, N_LABEL]
    const float* emb      = (const float*)d_in[4];
    const float* W1l      = (const float*)d_in[5];
    const float* W1r      = (const float*)d_in[6];
    const float* b1       = (const float*)d_in[7];
    const float* W2l      = (const float*)d_in[8];
    const float* W2r      = (const float*)d_in[9];
    const float* b2       = (const float*)d_in[10];
    float* out = (float*)d_out;

    const int* src = e_idx;
    const int* dst = e_idx + N_EDGES;

    const size_t HN = (size_t)N_NODES * DIM;       // 6.4M floats
    float* h0     = (float*)d_ws;
    float* h1     = h0 + HN;
    float* agg    = h1 + HN;
    int*   deg    = (int*)(agg + HN);
    int*   cursor = deg + N_NODES;
    int*   row    = cursor + N_NODES;              // N_NODES+1
    int*   csr    = row + N_NODES + 1;             // N_EDGES
    float* h2     = h0;                            // h0 dead after layer-1 linear

    hipMemsetAsync(deg, 0, N_NODES * sizeof(int), stream);
    hipMemsetAsync(cursor, 0, N_NODES * sizeof(int), stream);

    build_h0<<<(N_NODES * 32 + 255) / 256, 256, 0, stream>>>(n_id, emb, x_struct, h0);

    // CSR build (once; reused by both layers)
    deg_count<<<(N_EDGES + 255) / 256, 256, 0, stream>>>(dst, deg);
    scan_deg<<<1, 1024, 0, stream>>>(deg, row);
    csr_fill<<<(N_EDGES + 255) / 256, 256, 0, stream>>>(src, dst, row, cursor, csr);

    // layer 1
    aggregate_csr<<<(N_NODES * 64 + 255) / 256, 256, 0, stream>>>(row, csr, h0, agg);
    linear_tiled<1><<<(N_NODES + BM - 1) / BM, 256, 0, stream>>>(
        agg, h0, W1l, W1r, b1, h1);

    // layer 2
    aggregate_csr<<<(N_NODES * 64 + 255) / 256, 256, 0, stream>>>(row, csr, h1, agg);
    linear_tiled<0><<<(N_NODES + BM - 1) / BM, 256, 0, stream>>>(
        agg, h1, W2l, W2r, b2, h2);

    edge_dot<<<(N_LABEL * 32 + 255) / 256, 256, 0, stream>>>(eli, eli + N_LABEL, h2, out);
}

// Round 4
// 399.420 us; speedup vs baseline: 8.9669x; 1.2327x over previous
//
#include <hip/hip_runtime.h>

#define N_NODES 50000
#define DIM     128
#define N_EDGES 800000
#define N_LABEL 200000

typedef __attribute__((ext_vector_type(8)))  short short8;    // 8 bf16 (4 VGPRs)
typedef __attribute__((ext_vector_type(16))) float floatx16;  // 32x32 MFMA acc

// split fp32 into bf16 hi + bf16 lo (x ~= hi + lo, rel err ~2^-17), RNE both
__device__ inline void f32_to_bf16x2(float x, unsigned short& hi, unsigned short& lo) {
    unsigned u  = __float_as_uint(x);
    unsigned rh = (u + 0x7FFFu + ((u >> 16) & 1u)) >> 16;
    hi = (unsigned short)rh;
    float hif = __uint_as_float(rh << 16);
    float r = x - hif;
    unsigned ul = __float_as_uint(r);
    unsigned rl = (ul + 0x7FFFu + ((ul >> 16) & 1u)) >> 16;
    lo = (unsigned short)rl;
}

// h0[i] = concat(emb[n_id[i]], x_struct[i]) ; one thread per float4 (32 per row)
__global__ void build_h0(const int* __restrict__ n_id,
                         const float* __restrict__ emb,
                         const float* __restrict__ xs,
                         float* __restrict__ h0) {
    int t = blockIdx.x * blockDim.x + threadIdx.x;
    if (t >= N_NODES * 32) return;
    int i = t >> 5, c = t & 31;
    float4 v;
    if (c < 16) {
        int nid = n_id[i];
        v = ((const float4*)emb)[nid * 16 + c];
    } else {
        v = ((const float4*)xs)[i * 16 + (c - 16)];
    }
    ((float4*)h0)[i * 32 + c] = v;
}

__global__ void deg_count(const int* __restrict__ dst, int* __restrict__ deg) {
    int e = blockIdx.x * blockDim.x + threadIdx.x;
    if (e < N_EDGES) atomicAdd(&deg[dst[e]], 1);
}

// ---- multi-block scan of deg -> row (exclusive) ----
__global__ void scan_block(const int* __restrict__ deg, int* __restrict__ row,
                           int* __restrict__ bsum) {
    __shared__ int wsum[16];
    int t = threadIdx.x;
    int i = blockIdx.x * 1024 + t;
    int lane = t & 63, wid = t >> 6;
    int v = (i < N_NODES) ? deg[i] : 0;
    int s = v;
#pragma unroll
    for (int off = 1; off < 64; off <<= 1) {
        int u = __shfl_up(s, off, 64);
        if (lane >= off) s += u;
    }
    if (lane == 63) wsum[wid] = s;
    __syncthreads();
    if (wid == 0 && lane < 16) {
        int ws2 = wsum[lane];
#pragma unroll
        for (int off = 1; off < 16; off <<= 1) {
            int u = __shfl_up(ws2, off, 64);
            if (lane >= off) ws2 += u;
        }
        wsum[lane] = ws2;
    }
    __syncthreads();
    int wbase = wid ? wsum[wid - 1] : 0;
    if (i < N_NODES) row[i] = wbase + s - v;
    if (t == 1023) bsum[blockIdx.x] = wsum[15];
}

__global__ void scan_tops(const int* __restrict__ bsum, int* __restrict__ boff,
                          int* __restrict__ row) {
    int lane = threadIdx.x;                 // 64 threads, 49 used
    int v = (lane < 49) ? bsum[lane] : 0;
    int s = v;
#pragma unroll
    for (int off = 1; off < 64; off <<= 1) {
        int u = __shfl_up(s, off, 64);
        if (lane >= off) s += u;
    }
    if (lane < 49) boff[lane] = s - v;
    if (lane == 63) row[N_NODES] = s;       // grand total (= N_EDGES)
}

__global__ void scan_add(int* __restrict__ row, const int* __restrict__ boff) {
    int i = blockIdx.x * 1024 + threadIdx.x;
    if (i < N_NODES) row[i] += boff[blockIdx.x];
}

__global__ void csr_fill(const int* __restrict__ src, const int* __restrict__ dst,
                         const int* __restrict__ row, int* __restrict__ cursor,
                         int* __restrict__ csr_src) {
    int e = blockIdx.x * blockDim.x + threadIdx.x;
    if (e >= N_EDGES) return;
    int d = dst[e];
    int pos = atomicAdd(&cursor[d], 1);
    csr_src[row[d] + pos] = src[e];
}

// gather-mean: one wave per node; lane holds float2 slice of the 128-dim row
__global__ void aggregate_csr(const int* __restrict__ row,
                              const int* __restrict__ csr_src,
                              const float* __restrict__ h,
                              float* __restrict__ agg) {
    int wv   = (blockIdx.x * blockDim.x + threadIdx.x) >> 6;
    int lane = threadIdx.x & 63;
    if (wv >= N_NODES) return;
    int beg = row[wv], end = row[wv + 1];
    float ax = 0.f, ay = 0.f;
    for (int b = beg; b < end; b += 64) {
        int cnt = min(64, end - b);
        int idx = (b + lane < end) ? csr_src[b + lane] : 0;
        for (int j = 0; j < cnt; ++j) {
            int s = __shfl(idx, j, 64);
            float2 v = ((const float2*)h)[s * 64 + lane];
            ax += v.x; ay += v.y;
        }
    }
    float rd = 1.0f / fmaxf((float)(end - beg), 1.0f);
    ((float2*)agg)[wv * 64 + lane] = make_float2(ax * rd, ay * rd);
}

// Pre-swizzle W1l,W1r,W2l,W2r into MFMA B-fragment order, bf16 hi/lo.
// Chunk t (16B) = [ly][p][ks][nt][lane]; element j: W[k=ks*16+(lane>>5)*8+j][n=nt*32+(lane&31)]
__global__ void wf_build(const float* __restrict__ W1l, const float* __restrict__ W1r,
                         const float* __restrict__ W2l, const float* __restrict__ W2r,
                         unsigned short* __restrict__ WfH, unsigned short* __restrict__ WfL) {
    int t = blockIdx.x * blockDim.x + threadIdx.x;    // 8192 chunks
    if (t >= 8192) return;
    int L  = t & 63;
    int nt = (t >> 6) & 3;
    int ks = (t >> 8) & 7;
    int p  = (t >> 11) & 1;
    int ly = t >> 12;
    const float* Ws[4] = {W1l, W1r, W2l, W2r};
    const float* W = Ws[ly * 2 + p];
    int n = nt * 32 + (L & 31);
    int kbase = ks * 16 + (L >> 5) * 8;
    short8 hv, lv;
#pragma unroll
    for (int j = 0; j < 8; ++j) {
        unsigned short hh, ll;
        f32_to_bf16x2(W[(kbase + j) * DIM + n], hh, ll);
        hv[j] = (short)hh;
        lv[j] = (short)ll;
    }
    *(short8*)(WfH + (size_t)t * 8) = hv;
    *(short8*)(WfL + (size_t)t * 8) = lv;
}

// out[M,128] = relu?( agg@Wl + h@Wr + b ) via 32x32x16 bf16 MFMA, hi/lo split.
// Block = 256 thr = 4 waves; block tile 64 rows x 128 cols; wave = 32 rows x 64 cols.
template <int RELU>
__global__ __launch_bounds__(256)
void linear_mfma(const float* __restrict__ agg,
                 const float* __restrict__ h,
                 const unsigned short* __restrict__ WfH,   // per-layer base
                 const unsigned short* __restrict__ WfL,
                 const float* __restrict__ b,
                 float* __restrict__ out) {
    int tid  = threadIdx.x;
    int lane = tid & 63;
    int w    = tid >> 6;
    int row0 = blockIdx.x * 64 + (w & 1) * 32;
    int colhalf = w >> 1;                      // 0/1 -> cols [0,64)/[64,128)
    int nt0 = colhalf * 2;
    int m  = row0 + (lane & 31);
    int mc = min(m, N_NODES - 1);
    int kh = lane >> 5;                        // k-half within MFMA K=16

    floatx16 acc0, acc1;
#pragma unroll
    for (int i = 0; i < 16; ++i) { acc0[i] = 0.f; acc1[i] = 0.f; }

    const float* Asrc[2] = {agg, h};
    for (int p = 0; p < 2; ++p) {
        const float* arow = Asrc[p] + (size_t)mc * DIM + kh * 8;
#pragma unroll
        for (int ks = 0; ks < 8; ++ks) {
            float4 a0 = *(const float4*)(arow + ks * 16);
            float4 a1 = *(const float4*)(arow + ks * 16 + 4);
            float av[8] = {a0.x, a0.y, a0.z, a0.w, a1.x, a1.y, a1.z, a1.w};
            short8 ah, al;
#pragma unroll
            for (int j = 0; j < 8; ++j) {
                unsigned short hh, ll;
                f32_to_bf16x2(av[j], hh, ll);
                ah[j] = (short)hh;
                al[j] = (short)ll;
            }
            int cbase = ((p * 8 + ks) * 4 + nt0) * 64 + lane;
            short8 bh0 = *(const short8*)(WfH + (size_t)cbase * 8);
            short8 bl0 = *(const short8*)(WfL + (size_t)cbase * 8);
            short8 bh1 = *(const short8*)(WfH + (size_t)(cbase + 64) * 8);
            short8 bl1 = *(const short8*)(WfL + (size_t)(cbase + 64) * 8);
            acc0 = __builtin_amdgcn_mfma_f32_32x32x16_bf16(ah, bh0, acc0, 0, 0, 0);
            acc0 = __builtin_amdgcn_mfma_f32_32x32x16_bf16(ah, bl0, acc0, 0, 0, 0);
            acc0 = __builtin_amdgcn_mfma_f32_32x32x16_bf16(al, bh0, acc0, 0, 0, 0);
            acc1 = __builtin_amdgcn_mfma_f32_32x32x16_bf16(ah, bh1, acc1, 0, 0, 0);
            acc1 = __builtin_amdgcn_mfma_f32_32x32x16_bf16(ah, bl1, acc1, 0, 0, 0);
            acc1 = __builtin_amdgcn_mfma_f32_32x32x16_bf16(al, bh1, acc1, 0, 0, 0);
        }
    }

    int col0 = colhalf * 64 + (lane & 31);
    float b0 = b[col0], b1 = b[col0 + 32];
#pragma unroll
    for (int reg = 0; reg < 16; ++reg) {
        int rloc = (reg & 3) + 8 * (reg >> 2) + 4 * kh;   // C/D row map (m74/m101)
        int rowg = row0 + rloc;
        if (rowg < N_NODES) {
            float v0 = acc0[reg] + b0;
            float v1 = acc1[reg] + b1;
            if (RELU) { v0 = fmaxf(v0, 0.f); v1 = fmaxf(v1, 0.f); }
            out[(size_t)rowg * DIM + col0]      = v0;
            out[(size_t)rowg * DIM + col0 + 32] = v1;
        }
    }
}

__global__ void edge_dot(const int* __restrict__ esrc, const int* __restrict__ edst,
                         const float* __restrict__ h2, float* __restrict__ out) {
    int t = blockIdx.x * blockDim.x + threadIdx.x;
    int e = t >> 5, c = t & 31;
    if (e >= N_LABEL) return;
    float4 a  = ((const float4*)h2)[esrc[e] * 32 + c];
    float4 bb = ((const float4*)h2)[edst[e] * 32 + c];
    float p = a.x * bb.x + a.y * bb.y + a.z * bb.z + a.w * bb.w;
#pragma unroll
    for (int off = 16; off; off >>= 1) p += __shfl_down(p, off, 32);
    if (c == 0) out[e] = p;
}

extern "C" void kernel_launch(void* const* d_in, const int* in_sizes, int n_in,
                              void* d_out, int out_size, void* d_ws, size_t ws_size,
                              hipStream_t stream) {
    const int*   n_id     = (const int*)d_in[0];
    const float* x_struct = (const float*)d_in[1];
    const int*   e_idx    = (const int*)d_in[2];   // [2, N_EDGES]
    const int*   eli      = (const int*)d_in[3];   // [2, N_LABEL]
    const float* emb      = (const float*)d_in[4];
    const float* W1l      = (const float*)d_in[5];
    const float* W1r      = (const float*)d_in[6];
    const float* b1       = (const float*)d_in[7];
    const float* W2l      = (const float*)d_in[8];
    const float* W2r      = (const float*)d_in[9];
    const float* b2       = (const float*)d_in[10];
    float* out = (float*)d_out;

    const int* src = e_idx;
    const int* dst = e_idx + N_EDGES;

    const size_t HN = (size_t)N_NODES * DIM;       // 6.4M floats
    float* h0     = (float*)d_ws;
    float* h1     = h0 + HN;
    float* agg    = h1 + HN;
    int*   deg    = (int*)(agg + HN);
    int*   cursor = deg + N_NODES;
    int*   row    = cursor + N_NODES;              // N_NODES+1
    int*   bsum   = row + N_NODES + 1;             // 64
    int*   boff   = bsum + 64;                     // 64
    int*   csr    = boff + 64;                     // N_EDGES
    uintptr_t wfa = ((uintptr_t)(csr + N_EDGES) + 15) & ~(uintptr_t)15;
    unsigned short* WfH = (unsigned short*)wfa;    // 2 layers * 32768 shorts
    unsigned short* WfL = WfH + 2 * 32768;
    float* h2     = h0;                            // h0 dead after aggregate-1

    hipMemsetAsync(deg, 0, N_NODES * sizeof(int), stream);
    hipMemsetAsync(cursor, 0, N_NODES * sizeof(int), stream);

    wf_build<<<32, 256, 0, stream>>>(W1l, W1r, W2l, W2r, WfH, WfL);
    build_h0<<<(N_NODES * 32 + 255) / 256, 256, 0, stream>>>(n_id, emb, x_struct, h0);

    // CSR build (once; reused by both layers)
    deg_count<<<(N_EDGES + 255) / 256, 256, 0, stream>>>(dst, deg);
    scan_block<<<49, 1024, 0, stream>>>(deg, row, bsum);
    scan_tops<<<1, 64, 0, stream>>>(bsum, boff, row);
    scan_add<<<49, 1024, 0, stream>>>(row, boff);
    csr_fill<<<(N_EDGES + 255) / 256, 256, 0, stream>>>(src, dst, row, cursor, csr);

    // layer 1
    aggregate_csr<<<(N_NODES * 64 + 255) / 256, 256, 0, stream>>>(row, csr, h0, agg);
    linear_mfma<1><<<(N_NODES + 63) / 64, 256, 0, stream>>>(
        agg, h0, WfH, WfL, b1, h1);

    // layer 2
    aggregate_csr<<<(N_NODES * 64 + 255) / 256, 256, 0, stream>>>(row, csr, h1, agg);
    linear_mfma<0><<<(N_NODES + 63) / 64, 256, 0, stream>>>(
        agg, h1, WfH + 32768, WfL + 32768, b2, h2);

    edge_dot<<<(N_LABEL * 32 + 255) / 256, 256, 0, stream>>>(eli, eli + N_LABEL, h2, out);
}

// Round 5
// 346.923 us; speedup vs baseline: 10.3238x; 1.1513x over previous
//
#include <hip/hip_runtime.h>

#define N_NODES 50000
#define DIM     128
#define N_EDGES 800000
#define N_LABEL 200000

typedef __attribute__((ext_vector_type(8)))  short short8;    // 8 bf16 (4 VGPRs)
typedef __attribute__((ext_vector_type(16))) float floatx16;  // 32x32 MFMA acc

// split fp32 into bf16 hi + bf16 lo (x ~= hi + lo, rel err ~2^-17), RNE both
__device__ inline void f32_to_bf16x2(float x, unsigned short& hi, unsigned short& lo) {
    unsigned u  = __float_as_uint(x);
    unsigned rh = (u + 0x7FFFu + ((u >> 16) & 1u)) >> 16;
    hi = (unsigned short)rh;
    float hif = __uint_as_float(rh << 16);
    float r = x - hif;
    unsigned ul = __float_as_uint(r);
    unsigned rl = (ul + 0x7FFFu + ((ul >> 16) & 1u)) >> 16;
    lo = (unsigned short)rl;
}

__device__ inline unsigned short f32_to_bf16(float x) {
    unsigned u = __float_as_uint(x);
    return (unsigned short)((u + 0x7FFFu + ((u >> 16) & 1u)) >> 16);
}

// pack 2 fp32 -> uint of 2 bf16 (lo = first elem, hi = second)
__device__ inline unsigned pack_bf16x2(float a, float b) {
    return (unsigned)f32_to_bf16(a) | ((unsigned)f32_to_bf16(b) << 16);
}

// h0 = concat(emb[n_id], x_struct), fp32 + packed-bf16 dual write
__global__ void build_h0(const int* __restrict__ n_id,
                         const float* __restrict__ emb,
                         const float* __restrict__ xs,
                         float* __restrict__ h0,
                         unsigned* __restrict__ hb0) {   // N_NODES*32 uints
    int t = blockIdx.x * blockDim.x + threadIdx.x;
    if (t >= N_NODES * 32) return;
    int i = t >> 5, c = t & 31;
    float4 v;
    if (c < 16) {
        int nid = n_id[i];
        v = ((const float4*)emb)[nid * 16 + c];
    } else {
        v = ((const float4*)xs)[i * 16 + (c - 16)];
    }
    ((float4*)h0)[i * 32 + c] = v;
    uint2 p;
    p.x = pack_bf16x2(v.x, v.y);
    p.y = pack_bf16x2(v.z, v.w);
    ((uint2*)hb0)[i * 32 + c] = p;
}

__global__ void deg_count(const int* __restrict__ dst, int* __restrict__ deg) {
    int e = blockIdx.x * blockDim.x + threadIdx.x;
    if (e < N_EDGES) atomicAdd(&deg[dst[e]], 1);
}

// ---- multi-block scan of deg -> row (exclusive) ----
__global__ void scan_block(const int* __restrict__ deg, int* __restrict__ row,
                           int* __restrict__ bsum) {
    __shared__ int wsum[16];
    int t = threadIdx.x;
    int i = blockIdx.x * 1024 + t;
    int lane = t & 63, wid = t >> 6;
    int v = (i < N_NODES) ? deg[i] : 0;
    int s = v;
#pragma unroll
    for (int off = 1; off < 64; off <<= 1) {
        int u = __shfl_up(s, off, 64);
        if (lane >= off) s += u;
    }
    if (lane == 63) wsum[wid] = s;
    __syncthreads();
    if (wid == 0 && lane < 16) {
        int ws2 = wsum[lane];
#pragma unroll
        for (int off = 1; off < 16; off <<= 1) {
            int u = __shfl_up(ws2, off, 64);
            if (lane >= off) ws2 += u;
        }
        wsum[lane] = ws2;
    }
    __syncthreads();
    int wbase = wid ? wsum[wid - 1] : 0;
    if (i < N_NODES) row[i] = wbase + s - v;
    if (t == 1023) bsum[blockIdx.x] = wsum[15];
}

__global__ void scan_tops(const int* __restrict__ bsum, int* __restrict__ boff,
                          int* __restrict__ row) {
    int lane = threadIdx.x;
    int v = (lane < 49) ? bsum[lane] : 0;
    int s = v;
#pragma unroll
    for (int off = 1; off < 64; off <<= 1) {
        int u = __shfl_up(s, off, 64);
        if (lane >= off) s += u;
    }
    if (lane < 49) boff[lane] = s - v;
    if (lane == 63) row[N_NODES] = s;
}

__global__ void scan_add(int* __restrict__ row, const int* __restrict__ boff) {
    int i = blockIdx.x * 1024 + threadIdx.x;
    if (i < N_NODES) row[i] += boff[blockIdx.x];
}

__global__ void csr_fill(const int* __restrict__ src, const int* __restrict__ dst,
                         const int* __restrict__ row, int* __restrict__ cursor,
                         int* __restrict__ csr_src) {
    int e = blockIdx.x * blockDim.x + threadIdx.x;
    if (e >= N_EDGES) return;
    int d = dst[e];
    int pos = atomicAdd(&cursor[d], 1);
    csr_src[row[d] + pos] = src[e];
}

__device__ inline float bf_lo(unsigned u) { return __uint_as_float(u << 16); }
__device__ inline float bf_hi(unsigned u) { return __uint_as_float(u & 0xFFFF0000u); }

// gather-mean from packed bf16 h; one wave per node, lane holds 2 elems (1 uint).
// Inner loop batched x4 for memory-level parallelism.
__global__ void aggregate_bf16(const int* __restrict__ row,
                               const int* __restrict__ csr_src,
                               const unsigned* __restrict__ hb,
                               float* __restrict__ agg) {
    int wv   = (blockIdx.x * blockDim.x + threadIdx.x) >> 6;
    int lane = threadIdx.x & 63;
    if (wv >= N_NODES) return;
    int beg = row[wv], end = row[wv + 1];
    float ax0 = 0.f, ay0 = 0.f, ax1 = 0.f, ay1 = 0.f;
    for (int b = beg; b < end; b += 64) {
        int cnt = min(64, end - b);
        int idx = (b + lane < end) ? csr_src[b + lane] : 0;
        int j = 0;
        for (; j + 4 <= cnt; j += 4) {
            int s0 = __shfl(idx, j,     64);
            int s1 = __shfl(idx, j + 1, 64);
            int s2 = __shfl(idx, j + 2, 64);
            int s3 = __shfl(idx, j + 3, 64);
            unsigned v0 = hb[s0 * 64 + lane];
            unsigned v1 = hb[s1 * 64 + lane];
            unsigned v2 = hb[s2 * 64 + lane];
            unsigned v3 = hb[s3 * 64 + lane];
            ax0 += bf_lo(v0); ay0 += bf_hi(v0);
            ax1 += bf_lo(v1); ay1 += bf_hi(v1);
            ax0 += bf_lo(v2); ay0 += bf_hi(v2);
            ax1 += bf_lo(v3); ay1 += bf_hi(v3);
        }
        for (; j < cnt; ++j) {
            int s = __shfl(idx, j, 64);
            unsigned v = hb[s * 64 + lane];
            ax0 += bf_lo(v); ay0 += bf_hi(v);
        }
    }
    float rd = 1.0f / fmaxf((float)(end - beg), 1.0f);
    ((float2*)agg)[wv * 64 + lane] =
        make_float2((ax0 + ax1) * rd, (ay0 + ay1) * rd);
}

// Pre-swizzle W1l,W1r,W2l,W2r into MFMA B-fragment order, bf16 hi/lo.
__global__ void wf_build(const float* __restrict__ W1l, const float* __restrict__ W1r,
                         const float* __restrict__ W2l, const float* __restrict__ W2r,
                         unsigned short* __restrict__ WfH, unsigned short* __restrict__ WfL) {
    int t = blockIdx.x * blockDim.x + threadIdx.x;    // 8192 chunks
    if (t >= 8192) return;
    int L  = t & 63;
    int nt = (t >> 6) & 3;
    int ks = (t >> 8) & 7;
    int p  = (t >> 11) & 1;
    int ly = t >> 12;
    const float* Ws[4] = {W1l, W1r, W2l, W2r};
    const float* W = Ws[ly * 2 + p];
    int n = nt * 32 + (L & 31);
    int kbase = ks * 16 + (L >> 5) * 8;
    short8 hv, lv;
#pragma unroll
    for (int j = 0; j < 8; ++j) {
        unsigned short hh, ll;
        f32_to_bf16x2(W[(kbase + j) * DIM + n], hh, ll);
        hv[j] = (short)hh;
        lv[j] = (short)ll;
    }
    *(short8*)(WfH + (size_t)t * 8) = hv;
    *(short8*)(WfL + (size_t)t * 8) = lv;
}

// out = relu?( agg@Wl + h@Wr + b ) via 32x32x16 bf16 MFMA, hi/lo split.
// WRITE_BF16: also emit packed-bf16 copy of out (consumed by next aggregation).
template <int RELU, int WRITE_BF16>
__global__ __launch_bounds__(256)
void linear_mfma(const float* __restrict__ agg,
                 const float* __restrict__ h,
                 const unsigned short* __restrict__ WfH,
                 const unsigned short* __restrict__ WfL,
                 const float* __restrict__ b,
                 float* __restrict__ out,
                 unsigned short* __restrict__ outb) {
    int tid  = threadIdx.x;
    int lane = tid & 63;
    int w    = tid >> 6;
    int row0 = blockIdx.x * 64 + (w & 1) * 32;
    int colhalf = w >> 1;
    int nt0 = colhalf * 2;
    int m  = row0 + (lane & 31);
    int mc = min(m, N_NODES - 1);
    int kh = lane >> 5;

    floatx16 acc0, acc1;
#pragma unroll
    for (int i = 0; i < 16; ++i) { acc0[i] = 0.f; acc1[i] = 0.f; }

    const float* Asrc[2] = {agg, h};
    for (int p = 0; p < 2; ++p) {
        const float* arow = Asrc[p] + (size_t)mc * DIM + kh * 8;
#pragma unroll
        for (int ks = 0; ks < 8; ++ks) {
            float4 a0 = *(const float4*)(arow + ks * 16);
            float4 a1 = *(const float4*)(arow + ks * 16 + 4);
            float av[8] = {a0.x, a0.y, a0.z, a0.w, a1.x, a1.y, a1.z, a1.w};
            short8 ah, al;
#pragma unroll
            for (int j = 0; j < 8; ++j) {
                unsigned short hh, ll;
                f32_to_bf16x2(av[j], hh, ll);
                ah[j] = (short)hh;
                al[j] = (short)ll;
            }
            int cbase = ((p * 8 + ks) * 4 + nt0) * 64 + lane;
            short8 bh0 = *(const short8*)(WfH + (size_t)cbase * 8);
            short8 bl0 = *(const short8*)(WfL + (size_t)cbase * 8);
            short8 bh1 = *(const short8*)(WfH + (size_t)(cbase + 64) * 8);
            short8 bl1 = *(const short8*)(WfL + (size_t)(cbase + 64) * 8);
            acc0 = __builtin_amdgcn_mfma_f32_32x32x16_bf16(ah, bh0, acc0, 0, 0, 0);
            acc0 = __builtin_amdgcn_mfma_f32_32x32x16_bf16(ah, bl0, acc0, 0, 0, 0);
            acc0 = __builtin_amdgcn_mfma_f32_32x32x16_bf16(al, bh0, acc0, 0, 0, 0);
            acc1 = __builtin_amdgcn_mfma_f32_32x32x16_bf16(ah, bh1, acc1, 0, 0, 0);
            acc1 = __builtin_amdgcn_mfma_f32_32x32x16_bf16(ah, bl1, acc1, 0, 0, 0);
            acc1 = __builtin_amdgcn_mfma_f32_32x32x16_bf16(al, bh1, acc1, 0, 0, 0);
        }
    }

    int col0 = colhalf * 64 + (lane & 31);
    float b0 = b[col0], b1 = b[col0 + 32];
#pragma unroll
    for (int reg = 0; reg < 16; ++reg) {
        int rloc = (reg & 3) + 8 * (reg >> 2) + 4 * kh;   // C/D row map (m74/m101)
        int rowg = row0 + rloc;
        if (rowg < N_NODES) {
            float v0 = acc0[reg] + b0;
            float v1 = acc1[reg] + b1;
            if (RELU) { v0 = fmaxf(v0, 0.f); v1 = fmaxf(v1, 0.f); }
            out[(size_t)rowg * DIM + col0]      = v0;
            out[(size_t)rowg * DIM + col0 + 32] = v1;
            if (WRITE_BF16) {
                outb[(size_t)rowg * DIM + col0]      = f32_to_bf16(v0);
                outb[(size_t)rowg * DIM + col0 + 32] = f32_to_bf16(v1);
            }
        }
    }
}

__global__ void edge_dot(const int* __restrict__ esrc, const int* __restrict__ edst,
                         const float* __restrict__ h2, float* __restrict__ out) {
    int t = blockIdx.x * blockDim.x + threadIdx.x;
    int e = t >> 5, c = t & 31;
    if (e >= N_LABEL) return;
    float4 a  = ((const float4*)h2)[esrc[e] * 32 + c];
    float4 bb = ((const float4*)h2)[edst[e] * 32 + c];
    float p = a.x * bb.x + a.y * bb.y + a.z * bb.z + a.w * bb.w;
#pragma unroll
    for (int off = 16; off; off >>= 1) p += __shfl_down(p, off, 32);
    if (c == 0) out[e] = p;
}

extern "C" void kernel_launch(void* const* d_in, const int* in_sizes, int n_in,
                              void* d_out, int out_size, void* d_ws, size_t ws_size,
                              hipStream_t stream) {
    const int*   n_id     = (const int*)d_in[0];
    const float* x_struct = (const float*)d_in[1];
    const int*   e_idx    = (const int*)d_in[2];   // [2, N_EDGES]
    const int*   eli      = (const int*)d_in[3];   // [2, N_LABEL]
    const float* emb      = (const float*)d_in[4];
    const float* W1l      = (const float*)d_in[5];
    const float* W1r      = (const float*)d_in[6];
    const float* b1       = (const float*)d_in[7];
    const float* W2l      = (const float*)d_in[8];
    const float* W2r      = (const float*)d_in[9];
    const float* b2       = (const float*)d_in[10];
    float* out = (float*)d_out;

    const int* src = e_idx;
    const int* dst = e_idx + N_EDGES;

    const size_t HN = (size_t)N_NODES * DIM;       // 6.4M floats
    float* h0     = (float*)d_ws;
    float* h1     = h0 + HN;
    float* agg    = h1 + HN;
    int*   deg    = (int*)(agg + HN);
    int*   cursor = deg + N_NODES;
    int*   row    = cursor + N_NODES;              // N_NODES+1
    int*   bsum   = row + N_NODES + 1;             // 64
    int*   boff   = bsum + 64;                     // 64
    int*   csr    = boff + 64;                     // N_EDGES
    uintptr_t wfa = ((uintptr_t)(csr + N_EDGES) + 15) & ~(uintptr_t)15;
    unsigned short* WfH = (unsigned short*)wfa;    // 2 layers * 32768 shorts
    unsigned short* WfL = WfH + 2 * 32768;
    unsigned* hb0 = (unsigned*)(WfL + 2 * 32768);  // N_NODES*64 uints (bf16 h0)
    unsigned* hb1 = hb0 + (size_t)N_NODES * 64;    // N_NODES*64 uints (bf16 h1)
    float* h2     = h0;                            // h0 dead after aggregate-1 + linear-1

    hipMemsetAsync(deg, 0, N_NODES * sizeof(int), stream);
    hipMemsetAsync(cursor, 0, N_NODES * sizeof(int), stream);

    wf_build<<<32, 256, 0, stream>>>(W1l, W1r, W2l, W2r, WfH, WfL);
    build_h0<<<(N_NODES * 32 + 255) / 256, 256, 0, stream>>>(n_id, emb, x_struct, h0, hb0);

    // CSR build (once; reused by both layers)
    deg_count<<<(N_EDGES + 255) / 256, 256, 0, stream>>>(dst, deg);
    scan_block<<<49, 1024, 0, stream>>>(deg, row, bsum);
    scan_tops<<<1, 64, 0, stream>>>(bsum, boff, row);
    scan_add<<<49, 1024, 0, stream>>>(row, boff);
    csr_fill<<<(N_EDGES + 255) / 256, 256, 0, stream>>>(src, dst, row, cursor, csr);

    // layer 1
    aggregate_bf16<<<(N_NODES * 64 + 255) / 256, 256, 0, stream>>>(row, csr, hb0, agg);
    linear_mfma<1, 1><<<(N_NODES + 63) / 64, 256, 0, stream>>>(
        agg, h0, WfH, WfL, b1, h1, (unsigned short*)hb1);

    // layer 2
    aggregate_bf16<<<(N_NODES * 64 + 255) / 256, 256, 0, stream>>>(row, csr, hb1, agg);
    linear_mfma<0, 0><<<(N_NODES + 63) / 64, 256, 0, stream>>>(
        agg, h1, WfH + 32768, WfL + 32768, b2, h2, nullptr);

    edge_dot<<<(N_LABEL * 32 + 255) / 256, 256, 0, stream>>>(eli, eli + N_LABEL, h2, out);
}

// Round 6
// 294.529 us; speedup vs baseline: 12.1603x; 1.1779x over previous
//
#include <hip/hip_runtime.h>

#define N_NODES 50000
#define DIM     128
#define N_EDGES 800000
#define N_LABEL 200000

// bucket partition params: bucket = dst >> 7 (128 nodes per bucket)
#define NBUCK 391          // ceil(50000/128)
#define NPBLK 250          // partition blocks
#define CHUNK 3200         // edges per partition block (250*3200 = 800000)
#define GHN   (NBUCK * NPBLK)   // 97750

typedef __attribute__((ext_vector_type(8)))  short short8;    // 8 bf16 (4 VGPRs)
typedef __attribute__((ext_vector_type(16))) float floatx16;  // 32x32 MFMA acc

// split fp32 into bf16 hi + bf16 lo (x ~= hi + lo, rel err ~2^-17), RNE both
__device__ inline void f32_to_bf16x2(float x, unsigned short& hi, unsigned short& lo) {
    unsigned u  = __float_as_uint(x);
    unsigned rh = (u + 0x7FFFu + ((u >> 16) & 1u)) >> 16;
    hi = (unsigned short)rh;
    float hif = __uint_as_float(rh << 16);
    float r = x - hif;
    unsigned ul = __float_as_uint(r);
    unsigned rl = (ul + 0x7FFFu + ((ul >> 16) & 1u)) >> 16;
    lo = (unsigned short)rl;
}

__device__ inline unsigned short f32_to_bf16(float x) {
    unsigned u = __float_as_uint(x);
    return (unsigned short)((u + 0x7FFFu + ((u >> 16) & 1u)) >> 16);
}

__device__ inline unsigned pack_bf16x2(float a, float b) {
    return (unsigned)f32_to_bf16(a) | ((unsigned)f32_to_bf16(b) << 16);
}

// h0 = concat(emb[n_id], x_struct), fp32 + packed-bf16 dual write
__global__ void build_h0(const int* __restrict__ n_id,
                         const float* __restrict__ emb,
                         const float* __restrict__ xs,
                         float* __restrict__ h0,
                         unsigned* __restrict__ hb0) {
    int t = blockIdx.x * blockDim.x + threadIdx.x;
    if (t >= N_NODES * 32) return;
    int i = t >> 5, c = t & 31;
    float4 v;
    if (c < 16) {
        int nid = n_id[i];
        v = ((const float4*)emb)[nid * 16 + c];
    } else {
        v = ((const float4*)xs)[i * 16 + (c - 16)];
    }
    ((float4*)h0)[i * 32 + c] = v;
    uint2 p;
    p.x = pack_bf16x2(v.x, v.y);
    p.y = pack_bf16x2(v.z, v.w);
    ((uint2*)hb0)[i * 32 + c] = p;
}

// ---- bucket partition: replaces deg_count + csr_fill (no global atomics) ----

__global__ __launch_bounds__(256)
void part_hist(const int* __restrict__ dst, int* __restrict__ ghist) {
    __shared__ int hist[NBUCK];
    int t = threadIdx.x;
    for (int i = t; i < NBUCK; i += 256) hist[i] = 0;
    __syncthreads();
    int base = blockIdx.x * CHUNK;
    for (int e = base + t; e < base + CHUNK; e += 256)
        atomicAdd(&hist[dst[e] >> 7], 1);
    __syncthreads();
    for (int i = t; i < NBUCK; i += 256)
        ghist[i * NPBLK + blockIdx.x] = hist[i];
}

// generic multi-block exclusive scan (in-place), n <= 128*1024
__global__ void scan_block_n(int* __restrict__ data, int* __restrict__ bsum, int n) {
    __shared__ int wsum[16];
    int t = threadIdx.x;
    int i = blockIdx.x * 1024 + t;
    int lane = t & 63, wid = t >> 6;
    int v = (i < n) ? data[i] : 0;
    int s = v;
#pragma unroll
    for (int off = 1; off < 64; off <<= 1) {
        int u = __shfl_up(s, off, 64);
        if (lane >= off) s += u;
    }
    if (lane == 63) wsum[wid] = s;
    __syncthreads();
    if (wid == 0 && lane < 16) {
        int ws2 = wsum[lane];
#pragma unroll
        for (int off = 1; off < 16; off <<= 1) {
            int u = __shfl_up(ws2, off, 64);
            if (lane >= off) ws2 += u;
        }
        wsum[lane] = ws2;
    }
    __syncthreads();
    int wbase = wid ? wsum[wid - 1] : 0;
    if (i < n) data[i] = wbase + s - v;
    if (t == 1023) bsum[blockIdx.x] = wsum[15];
}

// scan of up to 128 block sums -> block offsets (1 block, 128 threads)
__global__ void scan_tops128(const int* __restrict__ bsum, int* __restrict__ boff, int n) {
    __shared__ int w0s;
    int t = threadIdx.x;
    int lane = t & 63, wid = t >> 6;
    int v = (t < n) ? bsum[t] : 0;
    int s = v;
#pragma unroll
    for (int off = 1; off < 64; off <<= 1) {
        int u = __shfl_up(s, off, 64);
        if (lane >= off) s += u;
    }
    if (t == 63) w0s = s;
    __syncthreads();
    int sf = s + (wid ? w0s : 0);
    if (t < n) boff[t] = sf - v;
}

__global__ void scan_add_n(int* __restrict__ data, const int* __restrict__ boff, int n) {
    int i = blockIdx.x * 1024 + threadIdx.x;
    if (i < n) data[i] += boff[blockIdx.x];
}

__global__ __launch_bounds__(256)
void part_scatter(const int* __restrict__ src, const int* __restrict__ dst,
                  const int* __restrict__ gbase, uint2* __restrict__ part) {
    __shared__ int cur[NBUCK];
    int t = threadIdx.x;
    for (int i = t; i < NBUCK; i += 256) cur[i] = gbase[i * NPBLK + blockIdx.x];
    __syncthreads();
    int base = blockIdx.x * CHUNK;
    for (int e = base + t; e < base + CHUNK; e += 256) {
        int d = dst[e];
        int pos = atomicAdd(&cur[d >> 7], 1);
        part[pos] = make_uint2((unsigned)src[e], (unsigned)(d & 127));
    }
}

// per-bucket: local deg count + LDS scan -> row[], then localized csr scatter
__global__ __launch_bounds__(256)
void bucket_csr(const uint2* __restrict__ part, const int* __restrict__ gbase,
                int* __restrict__ row, int* __restrict__ csr) {
    __shared__ int ldeg[128];
    __shared__ int lcur[128];
    __shared__ int w0s;
    int bk = blockIdx.x;
    int t = threadIdx.x;
    int beg = gbase[bk * NPBLK];
    int end = (bk + 1 < NBUCK) ? gbase[(bk + 1) * NPBLK] : N_EDGES;
    if (t < 128) ldeg[t] = 0;
    __syncthreads();
    for (int e = beg + t; e < end; e += 256)
        atomicAdd(&ldeg[part[e].y], 1);
    __syncthreads();
    int lane = t & 63, wid = t >> 6;
    int v = (t < 128) ? ldeg[t] : 0;
    int s = v;
#pragma unroll
    for (int off = 1; off < 64; off <<= 1) {
        int u = __shfl_up(s, off, 64);
        if (lane >= off) s += u;
    }
    if (t == 63) w0s = s;
    __syncthreads();
    if (t < 128) {
        int excl = s - v + ((wid == 1) ? w0s : 0);
        int node = bk * 128 + t;
        if (node < N_NODES) row[node] = beg + excl;
        lcur[t] = beg + excl;
    }
    if (bk == NBUCK - 1 && t == 0) row[N_NODES] = N_EDGES;
    __syncthreads();
    for (int e = beg + t; e < end; e += 256) {
        uint2 p = part[e];
        int pos = atomicAdd(&lcur[p.y], 1);
        csr[pos] = (int)p.x;
    }
}

__device__ inline float bf_lo(unsigned u) { return __uint_as_float(u << 16); }
__device__ inline float bf_hi(unsigned u) { return __uint_as_float(u & 0xFFFF0000u); }

// gather-mean from packed bf16 h; one wave per node, lane holds 2 elems (1 uint).
__global__ void aggregate_bf16(const int* __restrict__ row,
                               const int* __restrict__ csr_src,
                               const unsigned* __restrict__ hb,
                               float* __restrict__ agg) {
    int wv   = (blockIdx.x * blockDim.x + threadIdx.x) >> 6;
    int lane = threadIdx.x & 63;
    if (wv >= N_NODES) return;
    int beg = row[wv], end = row[wv + 1];
    float ax0 = 0.f, ay0 = 0.f, ax1 = 0.f, ay1 = 0.f;
    for (int b = beg; b < end; b += 64) {
        int cnt = min(64, end - b);
        int idx = (b + lane < end) ? csr_src[b + lane] : 0;
        int j = 0;
        for (; j + 4 <= cnt; j += 4) {
            int s0 = __shfl(idx, j,     64);
            int s1 = __shfl(idx, j + 1, 64);
            int s2 = __shfl(idx, j + 2, 64);
            int s3 = __shfl(idx, j + 3, 64);
            unsigned v0 = hb[s0 * 64 + lane];
            unsigned v1 = hb[s1 * 64 + lane];
            unsigned v2 = hb[s2 * 64 + lane];
            unsigned v3 = hb[s3 * 64 + lane];
            ax0 += bf_lo(v0); ay0 += bf_hi(v0);
            ax1 += bf_lo(v1); ay1 += bf_hi(v1);
            ax0 += bf_lo(v2); ay0 += bf_hi(v2);
            ax1 += bf_lo(v3); ay1 += bf_hi(v3);
        }
        for (; j < cnt; ++j) {
            int s = __shfl(idx, j, 64);
            unsigned v = hb[s * 64 + lane];
            ax0 += bf_lo(v); ay0 += bf_hi(v);
        }
    }
    float rd = 1.0f / fmaxf((float)(end - beg), 1.0f);
    ((float2*)agg)[wv * 64 + lane] =
        make_float2((ax0 + ax1) * rd, (ay0 + ay1) * rd);
}

// Pre-swizzle W1l,W1r,W2l,W2r into MFMA B-fragment order, bf16 hi/lo.
__global__ void wf_build(const float* __restrict__ W1l, const float* __restrict__ W1r,
                         const float* __restrict__ W2l, const float* __restrict__ W2r,
                         unsigned short* __restrict__ WfH, unsigned short* __restrict__ WfL) {
    int t = blockIdx.x * blockDim.x + threadIdx.x;    // 8192 chunks
    if (t >= 8192) return;
    int L  = t & 63;
    int nt = (t >> 6) & 3;
    int ks = (t >> 8) & 7;
    int p  = (t >> 11) & 1;
    int ly = t >> 12;
    const float* Ws[4] = {W1l, W1r, W2l, W2r};
    const float* W = Ws[ly * 2 + p];
    int n = nt * 32 + (L & 31);
    int kbase = ks * 16 + (L >> 5) * 8;
    short8 hv, lv;
#pragma unroll
    for (int j = 0; j < 8; ++j) {
        unsigned short hh, ll;
        f32_to_bf16x2(W[(kbase + j) * DIM + n], hh, ll);
        hv[j] = (short)hh;
        lv[j] = (short)ll;
    }
    *(short8*)(WfH + (size_t)t * 8) = hv;
    *(short8*)(WfL + (size_t)t * 8) = lv;
}

// out = relu?( agg@Wl + h@Wr + b ) via 32x32x16 bf16 MFMA, hi/lo split.
template <int RELU, int WRITE_BF16>
__global__ __launch_bounds__(256)
void linear_mfma(const float* __restrict__ agg,
                 const float* __restrict__ h,
                 const unsigned short* __restrict__ WfH,
                 const unsigned short* __restrict__ WfL,
                 const float* __restrict__ b,
                 float* __restrict__ out,
                 unsigned short* __restrict__ outb) {
    int tid  = threadIdx.x;
    int lane = tid & 63;
    int w    = tid >> 6;
    int row0 = blockIdx.x * 64 + (w & 1) * 32;
    int colhalf = w >> 1;
    int nt0 = colhalf * 2;
    int m  = row0 + (lane & 31);
    int mc = min(m, N_NODES - 1);
    int kh = lane >> 5;

    floatx16 acc0, acc1;
#pragma unroll
    for (int i = 0; i < 16; ++i) { acc0[i] = 0.f; acc1[i] = 0.f; }

    const float* Asrc[2] = {agg, h};
    for (int p = 0; p < 2; ++p) {
        const float* arow = Asrc[p] + (size_t)mc * DIM + kh * 8;
#pragma unroll
        for (int ks = 0; ks < 8; ++ks) {
            float4 a0 = *(const float4*)(arow + ks * 16);
            float4 a1 = *(const float4*)(arow + ks * 16 + 4);
            float av[8] = {a0.x, a0.y, a0.z, a0.w, a1.x, a1.y, a1.z, a1.w};
            short8 ah, al;
#pragma unroll
            for (int j = 0; j < 8; ++j) {
                unsigned short hh, ll;
                f32_to_bf16x2(av[j], hh, ll);
                ah[j] = (short)hh;
                al[j] = (short)ll;
            }
            int cbase = ((p * 8 + ks) * 4 + nt0) * 64 + lane;
            short8 bh0 = *(const short8*)(WfH + (size_t)cbase * 8);
            short8 bl0 = *(const short8*)(WfL + (size_t)cbase * 8);
            short8 bh1 = *(const short8*)(WfH + (size_t)(cbase + 64) * 8);
            short8 bl1 = *(const short8*)(WfL + (size_t)(cbase + 64) * 8);
            acc0 = __builtin_amdgcn_mfma_f32_32x32x16_bf16(ah, bh0, acc0, 0, 0, 0);
            acc0 = __builtin_amdgcn_mfma_f32_32x32x16_bf16(ah, bl0, acc0, 0, 0, 0);
            acc0 = __builtin_amdgcn_mfma_f32_32x32x16_bf16(al, bh0, acc0, 0, 0, 0);
            acc1 = __builtin_amdgcn_mfma_f32_32x32x16_bf16(ah, bh1, acc1, 0, 0, 0);
            acc1 = __builtin_amdgcn_mfma_f32_32x32x16_bf16(ah, bl1, acc1, 0, 0, 0);
            acc1 = __builtin_amdgcn_mfma_f32_32x32x16_bf16(al, bh1, acc1, 0, 0, 0);
        }
    }

    int col0 = colhalf * 64 + (lane & 31);
    float b0 = b[col0], b1 = b[col0 + 32];
#pragma unroll
    for (int reg = 0; reg < 16; ++reg) {
        int rloc = (reg & 3) + 8 * (reg >> 2) + 4 * kh;   // C/D row map (m74/m101)
        int rowg = row0 + rloc;
        if (rowg < N_NODES) {
            float v0 = acc0[reg] + b0;
            float v1 = acc1[reg] + b1;
            if (RELU) { v0 = fmaxf(v0, 0.f); v1 = fmaxf(v1, 0.f); }
            out[(size_t)rowg * DIM + col0]      = v0;
            out[(size_t)rowg * DIM + col0 + 32] = v1;
            if (WRITE_BF16) {
                outb[(size_t)rowg * DIM + col0]      = f32_to_bf16(v0);
                outb[(size_t)rowg * DIM + col0 + 32] = f32_to_bf16(v1);
            }
        }
    }
}

__global__ void edge_dot(const int* __restrict__ esrc, const int* __restrict__ edst,
                         const float* __restrict__ h2, float* __restrict__ out) {
    int t = blockIdx.x * blockDim.x + threadIdx.x;
    int e = t >> 5, c = t & 31;
    if (e >= N_LABEL) return;
    float4 a  = ((const float4*)h2)[esrc[e] * 32 + c];
    float4 bb = ((const float4*)h2)[edst[e] * 32 + c];
    float p = a.x * bb.x + a.y * bb.y + a.z * bb.z + a.w * bb.w;
#pragma unroll
    for (int off = 16; off; off >>= 1) p += __shfl_down(p, off, 32);
    if (c == 0) out[e] = p;
}

extern "C" void kernel_launch(void* const* d_in, const int* in_sizes, int n_in,
                              void* d_out, int out_size, void* d_ws, size_t ws_size,
                              hipStream_t stream) {
    const int*   n_id     = (const int*)d_in[0];
    const float* x_struct = (const float*)d_in[1];
    const int*   e_idx    = (const int*)d_in[2];   // [2, N_EDGES]
    const int*   eli      = (const int*)d_in[3];   // [2, N_LABEL]
    const float* emb      = (const float*)d_in[4];
    const float* W1l      = (const float*)d_in[5];
    const float* W1r      = (const float*)d_in[6];
    const float* b1       = (const float*)d_in[7];
    const float* W2l      = (const float*)d_in[8];
    const float* W2r      = (const float*)d_in[9];
    const float* b2       = (const float*)d_in[10];
    float* out = (float*)d_out;

    const int* src = e_idx;
    const int* dst = e_idx + N_EDGES;

    const size_t HN = (size_t)N_NODES * DIM;       // 6.4M floats
    float* h0    = (float*)d_ws;
    float* h1    = h0 + HN;
    float* agg   = h1 + HN;
    int*   row   = (int*)(agg + HN);               // N_NODES+1
    int*   ghist = row + N_NODES + 1;              // GHN
    int*   bsum  = ghist + GHN;                    // 128
    int*   boff  = bsum + 128;                     // 128
    int*   csr   = boff + 128;                     // N_EDGES
    uintptr_t pa = ((uintptr_t)(csr + N_EDGES) + 15) & ~(uintptr_t)15;
    uint2* part  = (uint2*)pa;                     // N_EDGES (src, dst&127)
    unsigned short* WfH = (unsigned short*)(part + N_EDGES);  // 2 layers * 32768
    unsigned short* WfL = WfH + 2 * 32768;
    unsigned* hb0 = (unsigned*)(WfL + 2 * 32768);  // N_NODES*64 uints (bf16 h0)
    unsigned* hb1 = hb0 + (size_t)N_NODES * 64;    // N_NODES*64 uints (bf16 h1)
    float* h2     = h0;                            // h0 dead after aggregate-1 + linear-1

    wf_build<<<32, 256, 0, stream>>>(W1l, W1r, W2l, W2r, WfH, WfL);
    build_h0<<<(N_NODES * 32 + 255) / 256, 256, 0, stream>>>(n_id, emb, x_struct, h0, hb0);

    // CSR build via LDS-bucket partition (once; reused by both layers)
    const int NSG = (GHN + 1023) / 1024;           // 96 scan blocks
    part_hist<<<NPBLK, 256, 0, stream>>>(dst, ghist);
    scan_block_n<<<NSG, 1024, 0, stream>>>(ghist, bsum, GHN);
    scan_tops128<<<1, 128, 0, stream>>>(bsum, boff, NSG);
    scan_add_n<<<NSG, 1024, 0, stream>>>(ghist, boff, GHN);
    part_scatter<<<NPBLK, 256, 0, stream>>>(src, dst, ghist, part);
    bucket_csr<<<NBUCK, 256, 0, stream>>>(part, ghist, row, csr);

    // layer 1
    aggregate_bf16<<<(N_NODES * 64 + 255) / 256, 256, 0, stream>>>(row, csr, hb0, agg);
    linear_mfma<1, 1><<<(N_NODES + 63) / 64, 256, 0, stream>>>(
        agg, h0, WfH, WfL, b1, h1, (unsigned short*)hb1);

    // layer 2
    aggregate_bf16<<<(N_NODES * 64 + 255) / 256, 256, 0, stream>>>(row, csr, hb1, agg);
    linear_mfma<0, 0><<<(N_NODES + 63) / 64, 256, 0, stream>>>(
        agg, h1, WfH + 32768, WfL + 32768, b2, h2, nullptr);

    edge_dot<<<(N_LABEL * 32 + 255) / 256, 256, 0, stream>>>(eli, eli + N_LABEL, h2, out);
}

// Round 7
// 290.015 us; speedup vs baseline: 12.3495x; 1.0156x over previous
//
#include <hip/hip_runtime.h>

#define N_NODES 50000
#define DIM     128
#define N_EDGES 800000
#define N_LABEL 200000

// bucket partition: bucket = dst >> 7 (128 nodes/bucket), fixed capacity slots
#define NBUCK 391            // ceil(50000/128)
#define CAP   4096           // slots per bucket (mean fill ~2046, 40-sigma margin)
#define NPBLK 250            // partition blocks
#define CHUNK 3200           // edges per partition block

typedef __attribute__((ext_vector_type(8)))  short short8;    // 8 bf16 (4 VGPRs)
typedef __attribute__((ext_vector_type(16))) float floatx16;  // 32x32 MFMA acc

// split fp32 into bf16 hi + bf16 lo (x ~= hi + lo, rel err ~2^-17), RNE both
__device__ inline void f32_to_bf16x2(float x, unsigned short& hi, unsigned short& lo) {
    unsigned u  = __float_as_uint(x);
    unsigned rh = (u + 0x7FFFu + ((u >> 16) & 1u)) >> 16;
    hi = (unsigned short)rh;
    float hif = __uint_as_float(rh << 16);
    float r = x - hif;
    unsigned ul = __float_as_uint(r);
    unsigned rl = (ul + 0x7FFFu + ((ul >> 16) & 1u)) >> 16;
    lo = (unsigned short)rl;
}

__device__ inline unsigned short f32_to_bf16(float x) {
    unsigned u = __float_as_uint(x);
    return (unsigned short)((u + 0x7FFFu + ((u >> 16) & 1u)) >> 16);
}

__device__ inline unsigned pack_bf16x2(float a, float b) {
    return (unsigned)f32_to_bf16(a) | ((unsigned)f32_to_bf16(b) << 16);
}

__device__ inline float bf_lo(unsigned u) { return __uint_as_float(u << 16); }
__device__ inline float bf_hi(unsigned u) { return __uint_as_float(u & 0xFFFF0000u); }

// fused: blocks [0,6250) build h0 (fp32 + bf16); blocks [6250,6282) swizzle W
__global__ __launch_bounds__(256)
void build_h0_wf(const int* __restrict__ n_id,
                 const float* __restrict__ emb,
                 const float* __restrict__ xs,
                 float* __restrict__ h0,
                 unsigned* __restrict__ hb0,
                 const float* __restrict__ W1l, const float* __restrict__ W1r,
                 const float* __restrict__ W2l, const float* __restrict__ W2r,
                 unsigned short* __restrict__ WfH, unsigned short* __restrict__ WfL) {
    if (blockIdx.x < 6250) {
        int t = blockIdx.x * 256 + threadIdx.x;     // < N_NODES*32 exactly
        int i = t >> 5, c = t & 31;
        float4 v;
        if (c < 16) {
            int nid = n_id[i];
            v = ((const float4*)emb)[nid * 16 + c];
        } else {
            v = ((const float4*)xs)[i * 16 + (c - 16)];
        }
        ((float4*)h0)[i * 32 + c] = v;
        uint2 p;
        p.x = pack_bf16x2(v.x, v.y);
        p.y = pack_bf16x2(v.z, v.w);
        ((uint2*)hb0)[i * 32 + c] = p;
    } else {
        int t = (blockIdx.x - 6250) * 256 + threadIdx.x;   // 8192 chunks
        if (t >= 8192) return;
        int L  = t & 63;
        int nt = (t >> 6) & 3;
        int ks = (t >> 8) & 7;
        int p  = (t >> 11) & 1;
        int ly = t >> 12;
        const float* Ws[4] = {W1l, W1r, W2l, W2r};
        const float* W = Ws[ly * 2 + p];
        int n = nt * 32 + (L & 31);
        int kbase = ks * 16 + (L >> 5) * 8;
        short8 hv, lv;
#pragma unroll
        for (int j = 0; j < 8; ++j) {
            unsigned short hh, ll;
            f32_to_bf16x2(W[(kbase + j) * DIM + n], hh, ll);
            hv[j] = (short)hh;
            lv[j] = (short)ll;
        }
        *(short8*)(WfH + (size_t)t * 8) = hv;
        *(short8*)(WfL + (size_t)t * 8) = lv;
    }
}

// fused hist + range-reserve + grouped scatter (no global scan)
__global__ __launch_bounds__(256)
void part_scatter(const int* __restrict__ src, const int* __restrict__ dst,
                  int* __restrict__ bcount, uint2* __restrict__ part) {
    __shared__ int hist[NBUCK];      // pass1: counts; pass2: write cursors
    int t = threadIdx.x;
    for (int i = t; i < NBUCK; i += 256) hist[i] = 0;
    __syncthreads();
    int base = blockIdx.x * CHUNK;
    for (int e = base + t; e < base + CHUNK; e += 256)
        atomicAdd(&hist[dst[e] >> 7], 1);
    __syncthreads();
    for (int i = t; i < NBUCK; i += 256) {
        int c = hist[i];
        hist[i] = c ? atomicAdd(&bcount[i], c) : 0;   // reserve [base, base+c)
    }
    __syncthreads();
    for (int e = base + t; e < base + CHUNK; e += 256) {
        int d = dst[e];
        int bk = d >> 7;
        int pos = atomicAdd(&hist[bk], 1);
        part[bk * CAP + pos] = make_uint2((unsigned)src[e], (unsigned)(d & 127));
    }
}

// per-bucket: local deg + LDS scan -> nbeg/nend, then localized csr scatter
__global__ __launch_bounds__(256)
void bucket_csr(const uint2* __restrict__ part, const int* __restrict__ bcount,
                int* __restrict__ nbeg, int* __restrict__ nend, int* __restrict__ csr) {
    __shared__ int ldeg[128];
    __shared__ int lcur[128];
    __shared__ int w0s;
    int bk = blockIdx.x;
    int t = threadIdx.x;
    int cnt = bcount[bk];
    int base = bk * CAP;
    if (t < 128) ldeg[t] = 0;
    __syncthreads();
    for (int e = t; e < cnt; e += 256)
        atomicAdd(&ldeg[part[base + e].y], 1);
    __syncthreads();
    int lane = t & 63, wid = t >> 6;
    int v = (t < 128) ? ldeg[t] : 0;
    int s = v;
#pragma unroll
    for (int off = 1; off < 64; off <<= 1) {
        int u = __shfl_up(s, off, 64);
        if (lane >= off) s += u;
    }
    if (t == 63) w0s = s;
    __syncthreads();
    if (t < 128) {
        int excl = s - v + ((wid == 1) ? w0s : 0);
        int node = bk * 128 + t;
        int b0 = base + excl;
        if (node < N_NODES) { nbeg[node] = b0; nend[node] = b0 + v; }
        lcur[t] = b0;
    }
    __syncthreads();
    for (int e = t; e < cnt; e += 256) {
        uint2 p = part[base + e];
        int pos = atomicAdd(&lcur[p.y], 1);
        csr[pos] = (int)p.x;
    }
}

// gather-mean from packed bf16 h; one wave per node, 2 edges in flight per half-wave.
// lane: sub = lane>>5 (edge parity), c = lane&31 (feature quad via uint2)
__global__ void aggregate_bf16(const int* __restrict__ nbeg, const int* __restrict__ nend,
                               const int* __restrict__ csr_src,
                               const unsigned* __restrict__ hb,
                               float* __restrict__ agg) {
    int wv   = (blockIdx.x * blockDim.x + threadIdx.x) >> 6;
    int lane = threadIdx.x & 63;
    if (wv >= N_NODES) return;
    int beg = nbeg[wv], end = nend[wv];
    int sub = lane >> 5, c = lane & 31;
    const uint2* H = (const uint2*)hb;
    float f0 = 0.f, f1 = 0.f, f2 = 0.f, f3 = 0.f;
    for (int b = beg; b < end; b += 64) {
        int cnt = min(64, end - b);
        int idx = (b + lane < end) ? csr_src[b + lane] : 0;
        for (int j = 0; j < cnt; j += 8) {
#pragma unroll
            for (int tq = 0; tq < 4; ++tq) {
                int jj = j + 2 * tq + sub;
                if (jj < cnt) {
                    int s = __shfl(idx, jj, 64);
                    uint2 vv = H[s * 32 + c];
                    f0 += bf_lo(vv.x); f1 += bf_hi(vv.x);
                    f2 += bf_lo(vv.y); f3 += bf_hi(vv.y);
                }
            }
        }
    }
    // combine the two half-wave edge-subsets (same feature slice at lane^32)
    f0 += __shfl(f0, lane ^ 32, 64);
    f1 += __shfl(f1, lane ^ 32, 64);
    f2 += __shfl(f2, lane ^ 32, 64);
    f3 += __shfl(f3, lane ^ 32, 64);
    if (sub == 0) {
        float rd = 1.0f / fmaxf((float)(end - beg), 1.0f);
        ((float4*)agg)[wv * 32 + c] = make_float4(f0 * rd, f1 * rd, f2 * rd, f3 * rd);
    }
}

// out = relu?( agg@Wl + h@Wr + b ) via 32x32x16 bf16 MFMA, hi/lo split.
template <int RELU, int WRITE_F32, int WRITE_BF16>
__global__ __launch_bounds__(256)
void linear_mfma(const float* __restrict__ agg,
                 const float* __restrict__ h,
                 const unsigned short* __restrict__ WfH,
                 const unsigned short* __restrict__ WfL,
                 const float* __restrict__ b,
                 float* __restrict__ out,
                 unsigned short* __restrict__ outb) {
    int tid  = threadIdx.x;
    int lane = tid & 63;
    int w    = tid >> 6;
    int row0 = blockIdx.x * 64 + (w & 1) * 32;
    int colhalf = w >> 1;
    int nt0 = colhalf * 2;
    int m  = row0 + (lane & 31);
    int mc = min(m, N_NODES - 1);
    int kh = lane >> 5;

    floatx16 acc0, acc1;
#pragma unroll
    for (int i = 0; i < 16; ++i) { acc0[i] = 0.f; acc1[i] = 0.f; }

    const float* Asrc[2] = {agg, h};
    for (int p = 0; p < 2; ++p) {
        const float* arow = Asrc[p] + (size_t)mc * DIM + kh * 8;
#pragma unroll
        for (int ks = 0; ks < 8; ++ks) {
            float4 a0 = *(const float4*)(arow + ks * 16);
            float4 a1 = *(const float4*)(arow + ks * 16 + 4);
            float av[8] = {a0.x, a0.y, a0.z, a0.w, a1.x, a1.y, a1.z, a1.w};
            short8 ah, al;
#pragma unroll
            for (int j = 0; j < 8; ++j) {
                unsigned short hh, ll;
                f32_to_bf16x2(av[j], hh, ll);
                ah[j] = (short)hh;
                al[j] = (short)ll;
            }
            int cbase = ((p * 8 + ks) * 4 + nt0) * 64 + lane;
            short8 bh0 = *(const short8*)(WfH + (size_t)cbase * 8);
            short8 bl0 = *(const short8*)(WfL + (size_t)cbase * 8);
            short8 bh1 = *(const short8*)(WfH + (size_t)(cbase + 64) * 8);
            short8 bl1 = *(const short8*)(WfL + (size_t)(cbase + 64) * 8);
            acc0 = __builtin_amdgcn_mfma_f32_32x32x16_bf16(ah, bh0, acc0, 0, 0, 0);
            acc0 = __builtin_amdgcn_mfma_f32_32x32x16_bf16(ah, bl0, acc0, 0, 0, 0);
            acc0 = __builtin_amdgcn_mfma_f32_32x32x16_bf16(al, bh0, acc0, 0, 0, 0);
            acc1 = __builtin_amdgcn_mfma_f32_32x32x16_bf16(ah, bh1, acc1, 0, 0, 0);
            acc1 = __builtin_amdgcn_mfma_f32_32x32x16_bf16(ah, bl1, acc1, 0, 0, 0);
            acc1 = __builtin_amdgcn_mfma_f32_32x32x16_bf16(al, bh1, acc1, 0, 0, 0);
        }
    }

    int col0 = colhalf * 64 + (lane & 31);
    float b0 = b[col0], b1 = b[col0 + 32];
#pragma unroll
    for (int reg = 0; reg < 16; ++reg) {
        int rloc = (reg & 3) + 8 * (reg >> 2) + 4 * kh;   // C/D row map (m74/m101)
        int rowg = row0 + rloc;
        if (rowg < N_NODES) {
            float v0 = acc0[reg] + b0;
            float v1 = acc1[reg] + b1;
            if (RELU) { v0 = fmaxf(v0, 0.f); v1 = fmaxf(v1, 0.f); }
            if (WRITE_F32) {
                out[(size_t)rowg * DIM + col0]      = v0;
                out[(size_t)rowg * DIM + col0 + 32] = v1;
            }
            if (WRITE_BF16) {
                outb[(size_t)rowg * DIM + col0]      = f32_to_bf16(v0);
                outb[(size_t)rowg * DIM + col0 + 32] = f32_to_bf16(v1);
            }
        }
    }
}

// logits from packed-bf16 h2; 32 threads/edge, uint2 per lane
__global__ void edge_dot(const int* __restrict__ esrc, const int* __restrict__ edst,
                         const unsigned* __restrict__ hb2, float* __restrict__ out) {
    int t = blockIdx.x * blockDim.x + threadIdx.x;
    int e = t >> 5, c = t & 31;
    if (e >= N_LABEL) return;
    const uint2* H = (const uint2*)hb2;
    uint2 a  = H[esrc[e] * 32 + c];
    uint2 bb = H[edst[e] * 32 + c];
    float p = bf_lo(a.x) * bf_lo(bb.x) + bf_hi(a.x) * bf_hi(bb.x)
            + bf_lo(a.y) * bf_lo(bb.y) + bf_hi(a.y) * bf_hi(bb.y);
#pragma unroll
    for (int off = 16; off; off >>= 1) p += __shfl_down(p, off, 32);
    if (c == 0) out[e] = p;
}

extern "C" void kernel_launch(void* const* d_in, const int* in_sizes, int n_in,
                              void* d_out, int out_size, void* d_ws, size_t ws_size,
                              hipStream_t stream) {
    const int*   n_id     = (const int*)d_in[0];
    const float* x_struct = (const float*)d_in[1];
    const int*   e_idx    = (const int*)d_in[2];   // [2, N_EDGES]
    const int*   eli      = (const int*)d_in[3];   // [2, N_LABEL]
    const float* emb      = (const float*)d_in[4];
    const float* W1l      = (const float*)d_in[5];
    const float* W1r      = (const float*)d_in[6];
    const float* b1       = (const float*)d_in[7];
    const float* W2l      = (const float*)d_in[8];
    const float* W2r      = (const float*)d_in[9];
    const float* b2       = (const float*)d_in[10];
    float* out = (float*)d_out;

    const int* src = e_idx;
    const int* dst = e_idx + N_EDGES;

    const size_t HN = (size_t)N_NODES * DIM;       // 6.4M floats
    float* h0     = (float*)d_ws;
    float* h1     = h0 + HN;
    float* agg    = h1 + HN;
    unsigned* hb0 = (unsigned*)(agg + HN);         // N_NODES*64 uints
    unsigned* hb1 = hb0 + (size_t)N_NODES * 64;
    int*   nbeg   = (int*)(hb1 + (size_t)N_NODES * 64);
    int*   nend   = nbeg + N_NODES;
    int*   bcount = nend + N_NODES;                // NBUCK
    int*   csr    = bcount + NBUCK;                // NBUCK*CAP
    uintptr_t pa  = ((uintptr_t)(csr + NBUCK * CAP) + 15) & ~(uintptr_t)15;
    uint2* part   = (uint2*)pa;                    // NBUCK*CAP (src, dst&127)
    unsigned short* WfH = (unsigned short*)(part + NBUCK * CAP);  // 2*32768
    unsigned short* WfL = WfH + 2 * 32768;
    unsigned* hb2 = hb0;                           // hb0 dead after aggregate-1

    hipMemsetAsync(bcount, 0, NBUCK * sizeof(int), stream);

    build_h0_wf<<<6250 + 32, 256, 0, stream>>>(n_id, emb, x_struct, h0, hb0,
                                               W1l, W1r, W2l, W2r, WfH, WfL);

    // CSR build: 2 kernels, fixed-capacity buckets, no global scan
    part_scatter<<<NPBLK, 256, 0, stream>>>(src, dst, bcount, part);
    bucket_csr<<<NBUCK, 256, 0, stream>>>(part, bcount, nbeg, nend, csr);

    // layer 1
    aggregate_bf16<<<(N_NODES * 64 + 255) / 256, 256, 0, stream>>>(nbeg, nend, csr, hb0, agg);
    linear_mfma<1, 1, 1><<<(N_NODES + 63) / 64, 256, 0, stream>>>(
        agg, h0, WfH, WfL, b1, h1, (unsigned short*)hb1);

    // layer 2 (fp32 output not needed — edge_dot reads bf16)
    aggregate_bf16<<<(N_NODES * 64 + 255) / 256, 256, 0, stream>>>(nbeg, nend, csr, hb1, agg);
    linear_mfma<0, 0, 1><<<(N_NODES + 63) / 64, 256, 0, stream>>>(
        agg, h1, WfH + 32768, WfL + 32768, b2, nullptr, (unsigned short*)hb2);

    edge_dot<<<(N_LABEL * 32 + 255) / 256, 256, 0, stream>>>(eli, eli + N_LABEL, hb2, out);
}